// Round 7
// baseline (403.275 us; speedup 1.0000x reference)
//
#include <hip/hip_runtime.h>

// Problem dims
#define H_  256
#define I_  128
#define R_  32
#define B_  16
#define T_  48
#define H3_ 768

// d_out float offsets: (v, h, dU, trace_e, trace_E, outs, mods)
#define OFF_V    0
#define OFF_H    4096
#define OFF_DU   8192
#define OFF_TE   1056768
#define OFF_TT   1060864
#define OFF_OUTS 2109440
#define OFF_MODS 2306048

#define BAR_STRIDE 32          // ints; 128B between group counter regions

typedef unsigned long long u64;

// Module-static scratch (allocated at .so load; zero-init).
__device__ __align__(16) float g_wx[T_*B_*H3_];   // LN(x@Wx^T+b) precomputed
// Packed (tag<<32 | float_bits) mailboxes: tag==t means "value for step t".
__device__ __align__(16) u64 g_whp[2*B_*H3_];     // double-buffered h@Wh^T (+bias)
__device__ __align__(16) u64 g_plp[2*B_*H_];      // double-buffered plastic
__device__ int g_bar[B_*BAR_STRIDE];              // init barrier counter; self-reset
__device__ int g_done[B_*BAR_STRIDE];

__device__ __forceinline__ float sigmf(float v){ return 1.0f/(1.0f+__expf(-v)); }

// Producer side: agent-scope store (PROVEN visible at the coherence point).
__device__ __forceinline__ void pstore(u64* p, int tag, float v){
  u64 u = ((u64)(unsigned)tag << 32) | (u64)__float_as_uint(v);
  __hip_atomic_store(p, u, __ATOMIC_RELAXED, __HIP_MEMORY_SCOPE_AGENT);
}
// Consumer side, guaranteed-progress round: agent-scope load.
__device__ __forceinline__ u64 pload(const u64* p){
  return __hip_atomic_load((u64*)p, __ATOMIC_RELAXED, __HIP_MEMORY_SCOPE_AGENT);
}
// Consumer side, opportunistic round: sc0 (L1-bypass, L2-serveable) loads.
// Stale data is HARMLESS: tag mismatch -> retry. Liveness comes from the
// interleaved agent rounds, so this can never hang regardless of sc0 semantics.
__device__ __forceinline__ void pload4_l2(const u64* p0, const u64* p1,
                                          const u64* p2, const u64* p3,
                                          u64& u0, u64& u1, u64& u2, u64& u3){
  asm volatile(
    "global_load_dwordx2 %0, %4, off sc0\n\t"
    "global_load_dwordx2 %1, %5, off sc0\n\t"
    "global_load_dwordx2 %2, %6, off sc0\n\t"
    "global_load_dwordx2 %3, %7, off sc0\n\t"
    "s_waitcnt vmcnt(0)"
    : "=&v"(u0), "=&v"(u1), "=&v"(u2), "=&v"(u3)
    : "v"(p0), "v"(p1), "v"(p2), "v"(p3)
    : "memory");
}

// Full barrier (init only): publishes plain g_wx stores via cache-wide fence.
__device__ __forceinline__ void groupbar_full(int* ctr, int target){
  __syncthreads();
  if (threadIdx.x == 0){
    __threadfence();                   // release: flush plain writes
    __hip_atomic_fetch_add(ctr, 1, __ATOMIC_RELAXED, __HIP_MEMORY_SCOPE_AGENT);
    while (__hip_atomic_load(ctr, __ATOMIC_RELAXED, __HIP_MEMORY_SCOPE_AGENT) < target)
      __builtin_amdgcn_s_sleep(1);
    __threadfence();                   // acquire: inv
  }
  __syncthreads();
}

__global__ __launch_bounds__(256, 1) void sgru_kernel(
    const float* __restrict__ x,     const float* __restrict__ h0,
    const float* __restrict__ v0,    const float* __restrict__ dU0,
    const float* __restrict__ te0,   const float* __restrict__ tE0,
    const float* __restrict__ Wx2h,  const float* __restrict__ bx2h,
    const float* __restrict__ Wh2h,  const float* __restrict__ bh2h,
    const float* __restrict__ lnxg,  const float* __restrict__ lnxb,
    const float* __restrict__ lnhg,  const float* __restrict__ lnhb,
    const float* __restrict__ Wh2mod,const float* __restrict__ bh2mod,
    const float* __restrict__ Wmod2h,const float* __restrict__ bmod2h,
    const float* __restrict__ alpha, const float* __restrict__ tauU,
    float* __restrict__ out)
{
  const int tid  = threadIdx.x;
  const int g    = blockIdx.x;
  // XCD-local grouping HEURISTIC (round-robin dispatch: XCD = g%8): group b's
  // 16 blocks all share g%8 -> likely same XCD -> sc0 poll rounds can hit L2.
  // Correctness does NOT depend on this (agent rounds guarantee progress).
  const int b    = (g & 7) + 8*(g >> 7);
  const int c    = (g >> 3) & 15;
  const int lane = tid & 63;
  const int wv   = tid >> 6;

  __shared__ __align__(16) float hn_s[H_], ten_s[H_];
  __shared__ __align__(16) float xst_s[3*I_];          // init-only x staging
  __shared__ __align__(16) float lnhg_s[H3_], lnhb_s[H3_];
  // Wh2h rows, swizzled so per-u ds_read_b128 is lane-contiguous (conflict-free).
  __shared__ __align__(16) float wrow_s[48*256];
  __shared__ float red_s[8];

  float* ws_wx = g_wx;
  int*   ctr   = g_bar  + b*BAR_STRIDE;
  int*   dctr  = g_done + b*BAR_STRIDE;

  const float sp_a    = log1pf(__expf(alpha[0]));   // softplus(alpha)
  const float inv_spa = 1.0f / sp_a;
  const float tau     = sigmf(tauU[0]);

  // ---------------- init: states + weight staging ----------------
  float h_r  = h0[b*H_+tid];
  float v_r  = v0[b*H_+tid];
  float te_r = te0[b*H_+tid];
  hn_s[tid] = h_r;                      // staging for init dots
  for (int idx = tid; idx < 48*64; idx += 256){
    int d = idx >> 6, j = idx & 63;
    float4 w4 = ((const float4*)(Wh2h + ((size_t)(c*48 + d))*H_))[j];
    ((float4*)wrow_s)[(d>>4)*1024 + (j>>2)*64 + (d&15)*4 + (j&3)] = w4;
  }
  for (int idx = tid; idx < H3_; idx += 256){
    lnhg_s[idx] = lnhg[idx];
    lnhb_s[idx] = lnhb[idx];
  }
  float4 upR[4], loR[4];                // precomputed clip bounds (loop-invariant)
  float4 duR[4], tER[4];                // PERSISTENT dU/tE fragments (my 16 rows)
  #pragma unroll
  for (int rr = 0; rr < 4; rr++){
    int i = c*16 + rr*4 + wv;
    float4 w = ((const float4*)(Wh2h + ((size_t)(2*H_ + i))*H_))[lane];
    upR[rr].x =  fmaxf(1.0f - w.x, 0.0f)*inv_spa;
    upR[rr].y =  fmaxf(1.0f - w.y, 0.0f)*inv_spa;
    upR[rr].z =  fmaxf(1.0f - w.z, 0.0f)*inv_spa;
    upR[rr].w =  fmaxf(1.0f - w.w, 0.0f)*inv_spa;
    loR[rr].x = -fmaxf(1.0f + w.x, 0.0f)*inv_spa;
    loR[rr].y = -fmaxf(1.0f + w.y, 0.0f)*inv_spa;
    loR[rr].z = -fmaxf(1.0f + w.z, 0.0f)*inv_spa;
    loR[rr].w = -fmaxf(1.0f + w.w, 0.0f)*inv_spa;
    size_t rowo = ((size_t)(b*H_ + i))*H_;
    duR[rr] = ((const float4*)(dU0 + rowo))[lane];
    tER[rr] = ((const float4*)(tE0 + rowo))[lane];
  }
  // mod weights: FULL Wh2mod in registers, per-wave redundant layout.
  // Lane l owns half-row: row = l&31, cols [(l>>5)*128, +128) as 32 float4.
  // (1 wave/SIMD via launch_bounds(256,1) -> up to 512 VGPR; no occupancy loss.)
  float4 wmv[32];
  {
    const float4* wr = (const float4*)(Wh2mod + (size_t)(lane & 31)*H_);
    #pragma unroll
    for (int k = 0; k < 32; k++) wmv[k] = wr[(lane>>5)*32 + k];
  }
  const float bh2m = bh2mod[lane & 31];
  const float wmA = Wmod2h[lane & 31];
  const float wmB = Wmod2h[R_ + (lane & 31)];
  const float bm0 = bmod2h[0], bm1 = bmod2h[1];
  float bh2h_reg = 0.f;
  if (tid < 192) bh2h_reg = bh2h[c*48 + (tid>>2)];
  __syncthreads();

  // ---- init: Wx_ln rows t = c*3+q for batch b (carry-independent)
  {
    float* xr = xst_s;   // [3][128]
    for (int idx = tid; idx < 3*I_; idx += 256){
      int q = idx >> 7, e = idx & 127;
      xr[q*I_ + e] = x[((size_t)((c*3+q)*B_ + b))*I_ + e];
    }
    __syncthreads();
    float acc[3][3];
    #pragma unroll
    for (int k = 0; k < 3; k++){
      acc[k][0]=0.f; acc[k][1]=0.f; acc[k][2]=0.f;
      int f = tid + 256*k;
      const float4* wr = (const float4*)(Wx2h + (size_t)f*I_);
      for (int e4 = 0; e4 < I_/4; e4++){
        float4 w4 = wr[e4];
        int e = e4*4;
        #pragma unroll
        for (int q = 0; q < 3; q++){
          float t0 = fmaf(w4.x, xr[q*I_+e],   acc[k][q]);
          t0       = fmaf(w4.y, xr[q*I_+e+1], t0);
          t0       = fmaf(w4.z, xr[q*I_+e+2], t0);
          acc[k][q]= fmaf(w4.w, xr[q*I_+e+3], t0);
        }
      }
      float bf = bx2h[f];
      acc[k][0]+=bf; acc[k][1]+=bf; acc[k][2]+=bf;
    }
    __syncthreads();
    for (int q = 0; q < 3; q++){
      float s1 = acc[0][q]+acc[1][q]+acc[2][q];
      float s2 = acc[0][q]*acc[0][q]+acc[1][q]*acc[1][q]+acc[2][q]*acc[2][q];
      #pragma unroll
      for (int off=32; off>0; off>>=1){ s1 += __shfl_xor(s1,off); s2 += __shfl_xor(s2,off); }
      if (lane==0){ red_s[wv]=s1; red_s[4+wv]=s2; }
      __syncthreads();
      s1 = red_s[0]+red_s[1]+red_s[2]+red_s[3];
      s2 = red_s[4]+red_s[5]+red_s[6]+red_s[7];
      __syncthreads();
      float mu  = s1*(1.0f/768.0f);
      float var = s2*(1.0f/768.0f) - mu*mu;
      float rs  = rsqrtf(var + 1e-5f);
      float* dst = ws_wx + ((size_t)((c*3+q)*B_ + b))*H3_;
      #pragma unroll
      for (int k = 0; k < 3; k++){
        int f = tid + 256*k;
        dst[f] = (acc[k][q]-mu)*rs*lnxg[f] + lnxb[f];
      }
    }
  }

  // ---- init: plastic_0 (tag 0) + Wh_raw_0 (tag 0), slot 0
  {
    const float4* h4 = (const float4*)hn_s;
    float4 hj = h4[lane];
    float a[4];
    #pragma unroll
    for (int rr = 0; rr < 4; rr++){
      float4 du = duR[rr];
      a[rr] = du.x*hj.x + du.y*hj.y + du.z*hj.z + du.w*hj.w;
    }
    #pragma unroll
    for (int off=32; off>0; off>>=1){
      a[0] += __shfl_xor(a[0],off); a[1] += __shfl_xor(a[1],off);
      a[2] += __shfl_xor(a[2],off); a[3] += __shfl_xor(a[3],off);
    }
    if (lane==0){
      #pragma unroll
      for (int rr = 0; rr < 4; rr++)
        pstore(&g_plp[b*H_ + c*16 + rr*4 + wv], 0, sp_a*a[rr]);
    }
    if (tid < 192){
      const int w  = tid >> 6;          // wave 0..2
      const int l4 = lane & 3;
      const float4* wb  = ((const float4*)wrow_s) + w*1024;
      const float4* hh4 = (const float4*)hn_s;
      float acc = 0.f;
      #pragma unroll
      for (int u = 0; u < 16; u++){
        float4 w4 = wb[u*64 + lane];          // lane-contiguous: conflict-free
        float4 hv = hh4[u*4 + l4];            // 4-addr broadcast
        acc = fmaf(w4.x,hv.x, fmaf(w4.y,hv.y, fmaf(w4.z,hv.z, fmaf(w4.w,hv.w, acc))));
      }
      acc += __shfl_xor(acc,1);
      acc += __shfl_xor(acc,2);
      if (l4==0) pstore(&g_whp[b*H3_ + c*48 + w*16 + (lane>>2)], 0, acc + bh2h_reg);
    }
  }
  groupbar_full(ctr, 16);

  // ---------------- scan: tag-fused mailboxes, 2 barriers/step ----------------
  for (int t = 0; t < T_; t++){
    const int p  = t & 1;
    const int pn = p ^ 1;

    const float* wxr = ws_wx + ((size_t)(t*B_ + b))*H3_;
    float wx0 = wxr[tid], wx1 = wxr[tid+256], wx2 = wxr[tid+512];

    // ---- poll: value+tag in one load; alternate sc0 (fast, opportunistic)
    //      and agent (guaranteed-progress) rounds. Hang-proof by construction.
    const u64* whp = g_whp + p*(B_*H3_) + b*H3_;
    const u64* plp = g_plp + p*(B_*H_)  + b*H_;
    u64 u0, u1, u2, u3;
    int round = 0;
    for(;;){
      if ((round & 1) == 0){
        pload4_l2(whp+tid, whp+tid+256, whp+tid+512, plp+tid, u0, u1, u2, u3);
      } else {
        u0 = pload(whp + tid);
        u1 = pload(whp + tid + 256);
        u2 = pload(whp + tid + 512);
        u3 = pload(plp + tid);
      }
      bool ok = ((int)(u0>>32)==t) && ((int)(u1>>32)==t) &&
                ((int)(u2>>32)==t) && ((int)(u3>>32)==t);
      if (__all(ok)) break;
      round++;
    }
    float wh0 = __uint_as_float((unsigned)u0);
    float wh1 = __uint_as_float((unsigned)u1);
    float wh2 = __uint_as_float((unsigned)u2) + __uint_as_float((unsigned)u3);

    // ---- LN + gates (state h/v/te in registers)
    float hn, ten;
    {
      float s1 = wh0+wh1+wh2;
      float s2 = wh0*wh0+wh1*wh1+wh2*wh2;
      #pragma unroll
      for (int off=32; off>0; off>>=1){ s1 += __shfl_xor(s1,off); s2 += __shfl_xor(s2,off); }
      if (lane==0){ red_s[wv]=s1; red_s[4+wv]=s2; }
      __syncthreads();                                   // sync #1
      s1 = red_s[0]+red_s[1]+red_s[2]+red_s[3];
      s2 = red_s[4]+red_s[5]+red_s[6]+red_s[7];
      float mu  = s1*(1.0f/768.0f);
      float var = s2*(1.0f/768.0f) - mu*mu;
      float rs  = rsqrtf(var + 1e-5f);
      float pre0 = wx0 + (wh0-mu)*rs*lnhg_s[tid]     + lnhb_s[tid];
      float pre1 = wx1 + (wh1-mu)*rs*lnhg_s[tid+256] + lnhb_s[tid+256];
      float pre2 = wx2 + (wh2-mu)*rs*lnhg_s[tid+512] + lnhb_s[tid+512];
      float z   = sigmf(pre0);
      float r   = sigmf(pre1);
      float vn  = fmaf(z, pre2 - v_r, v_r);     // (1-z)v + z dv
      hn  = fmaxf(vn, 0.0f);
      ten = fmaf(r, h_r - te_r, te_r);          // (1-r)te + r h_old
      v_r = vn; h_r = hn; te_r = ten;
      hn_s[tid] = hn; ten_s[tid] = ten;
    }
    __syncthreads();                                     // sync #2 (LAST of the step)

    // ---- hoisted U-phase LDS loads
    const float4* hn4 = (const float4*)hn_s;
    const float4* te4 = (const float4*)ten_s;
    float4 hj = hn4[lane];
    float4 tj = te4[lane];
    float hni[4], teni[4];
    #pragma unroll
    for (int rr = 0; rr < 4; rr++){
      int i = c*16 + rr*4 + wv;
      hni[rr]  = hn_s[i];
      teni[rr] = ten_s[i];
    }

    // ---- Wh(t+1): FIRST (publish as early as possible; R4-proven ordering).
    //      Wave 3 (tid>=192) skips this and races ahead to mod/s/m/U/pl.
    if (t < T_-1 && tid < 192){
      const int w  = tid >> 6;
      const int l4 = lane & 3;
      const float4* wb  = ((const float4*)wrow_s) + w*1024;
      float acc = 0.f;
      #pragma unroll
      for (int u = 0; u < 16; u++){
        float4 w4 = wb[u*64 + lane];
        float4 hv = hn4[u*4 + l4];
        acc = fmaf(w4.x,hv.x, fmaf(w4.y,hv.y, fmaf(w4.z,hv.z, fmaf(w4.w,hv.w, acc))));
      }
      acc += __shfl_xor(acc,1);
      acc += __shfl_xor(acc,2);
      if (l4==0) pstore(&g_whp[pn*(B_*H3_) + b*H3_ + c*48 + w*16 + (lane>>2)],
                        t+1, acc + bh2h_reg);
    }

    // ---- mod + s/m: per-wave redundant, fully in-register (NO barrier).
    //      Lane l: half-row (l&31), cols [(l>>5)*128,+128); xor(32) completes row.
    float modv;
    {
      const float4* hh = hn4 + (lane>>5)*32;
      float macc = 0.f;
      #pragma unroll
      for (int k = 0; k < 32; k++){
        float4 hv = hh[k];                 // broadcast within half-wave
        float4 w4 = wmv[k];
        macc = fmaf(w4.x,hv.x, fmaf(w4.y,hv.y, fmaf(w4.z,hv.z, fmaf(w4.w,hv.w, macc))));
      }
      macc += __shfl_xor(macc, 32);        // combine col-halves -> full row sum
      modv = fmaxf(macc + bh2m, 0.0f);     // mod[lane&31], both wave halves
    }
    float s_b, m_b;
    {
      float p0 = modv*wmA, p1 = modv*wmB;
      #pragma unroll
      for (int off=16; off>0; off>>=1){ p0 += __shfl_xor(p0,off); p1 += __shfl_xor(p1,off); }
      s_b = sigmf(p0 + bm0);
      m_b = p1 + bm1;
    }

    // ---- U phase: register-resident tE/dU update; pl publish ASAP
    float pacc[4];
    #pragma unroll
    for (int rr = 0; rr < 4; rr++){
      float4 du = duR[rr];
      float4 tE = tER[rr];
      float4 up = upR[rr];
      float4 lo = loR[rr];
      float h_i = hni[rr], t_i = teni[rr];
      float4 nd, nt;
      float acc;
      { float o_ = h_i*tj.x - t_i*hj.x;
        float tn = fmaf(s_b, o_ - tE.x, tE.x);
        float dn = fmaf(tau, fmaf(m_b, tn, -du.x), du.x);
        dn = fminf(dn, up.x); dn = fmaxf(dn, lo.x);
        nt.x = tn; nd.x = dn; acc = dn*hj.x; }
      { float o_ = h_i*tj.y - t_i*hj.y;
        float tn = fmaf(s_b, o_ - tE.y, tE.y);
        float dn = fmaf(tau, fmaf(m_b, tn, -du.y), du.y);
        dn = fminf(dn, up.y); dn = fmaxf(dn, lo.y);
        nt.y = tn; nd.y = dn; acc = fmaf(dn, hj.y, acc); }
      { float o_ = h_i*tj.z - t_i*hj.z;
        float tn = fmaf(s_b, o_ - tE.z, tE.z);
        float dn = fmaf(tau, fmaf(m_b, tn, -du.z), du.z);
        dn = fminf(dn, up.z); dn = fmaxf(dn, lo.z);
        nt.z = tn; nd.z = dn; acc = fmaf(dn, hj.z, acc); }
      { float o_ = h_i*tj.w - t_i*hj.w;
        float tn = fmaf(s_b, o_ - tE.w, tE.w);
        float dn = fmaf(tau, fmaf(m_b, tn, -du.w), du.w);
        dn = fminf(dn, up.w); dn = fmaxf(dn, lo.w);
        nt.w = tn; nd.w = dn; acc = fmaf(dn, hj.w, acc); }
      duR[rr] = nd;
      tER[rr] = nt;
      pacc[rr] = acc;
    }
    #pragma unroll
    for (int off=32; off>0; off>>=1){
      pacc[0] += __shfl_xor(pacc[0],off); pacc[1] += __shfl_xor(pacc[1],off);
      pacc[2] += __shfl_xor(pacc[2],off); pacc[3] += __shfl_xor(pacc[3],off);
    }
    if (t < T_-1 && lane==0){
      u64* pd = g_plp + pn*(B_*H_) + b*H_ + c*16 + wv;
      pstore(pd + 0,  t+1, sp_a*pacc[0]);
      pstore(pd + 4,  t+1, sp_a*pacc[1]);
      pstore(pd + 8,  t+1, sp_a*pacc[2]);
      pstore(pd + 12, t+1, sp_a*pacc[3]);
    }

    // ---- outputs: AFTER publishes (off the inter-block serial path)
    if (tid < 16) out[OFF_OUTS + ((size_t)(t*B_+b))*H_ + c*16 + tid] = hn_s[c*16 + tid];
    if (wv == 0 && (lane == c*2 || lane == c*2 + 1))
      out[OFF_MODS + (size_t)(t*B_+b)*R_ + lane] = modv;   // lane holds mod[lane]
    if (t == T_-1){
      #pragma unroll
      for (int rr = 0; rr < 4; rr++){
        int i = c*16 + rr*4 + wv;
        size_t rowo = ((size_t)(b*H_ + i))*H_;
        ((float4*)(out + OFF_DU + rowo))[lane] = duR[rr];
        ((float4*)(out + OFF_TT + rowo))[lane] = tER[rr];
      }
      if (c == 0){
        out[OFF_V  + b*H_ + tid] = v_r;
        out[OFF_H  + b*H_ + tid] = h_r;
        out[OFF_TE + b*H_ + tid] = te_r;
      }
    }
    // no end-of-step barrier: next iteration's poll + sync#1 enforce ordering
  }

  // ---- self-reset of group counters for the next launch.
  __syncthreads();
  if (threadIdx.x == 0){
    int d = __hip_atomic_fetch_add(dctr, 1, __ATOMIC_RELAXED, __HIP_MEMORY_SCOPE_AGENT);
    if (d == 15){
      __hip_atomic_store(ctr,  0, __ATOMIC_RELAXED, __HIP_MEMORY_SCOPE_AGENT);
      __hip_atomic_store(dctr, 0, __ATOMIC_RELAXED, __HIP_MEMORY_SCOPE_AGENT);
    }
  }
}

extern "C" void kernel_launch(void* const* d_in, const int* in_sizes, int n_in,
                              void* d_out, int out_size, void* d_ws, size_t ws_size,
                              hipStream_t stream)
{
  const float* x      = (const float*)d_in[0];
  const float* h0     = (const float*)d_in[1];
  const float* v0     = (const float*)d_in[2];
  const float* dU0    = (const float*)d_in[3];
  const float* te0    = (const float*)d_in[4];
  const float* tE0    = (const float*)d_in[5];
  const float* Wx2h   = (const float*)d_in[6];
  const float* bx2h   = (const float*)d_in[7];
  const float* Wh2h   = (const float*)d_in[8];
  const float* bh2h   = (const float*)d_in[9];
  const float* lnxg   = (const float*)d_in[10];
  const float* lnxb   = (const float*)d_in[11];
  const float* lnhg   = (const float*)d_in[12];
  const float* lnhb   = (const float*)d_in[13];
  const float* Wh2mod = (const float*)d_in[14];
  const float* bh2mod = (const float*)d_in[15];
  const float* Wmod2h = (const float*)d_in[16];
  const float* bmod2h = (const float*)d_in[17];
  const float* alpha  = (const float*)d_in[18];
  const float* tauU   = (const float*)d_in[19];
  float* out = (float*)d_out;

  sgru_kernel<<<dim3(256), dim3(256), 0, stream>>>(
      x, h0, v0, dU0, te0, tE0, Wx2h, bx2h, Wh2h, bh2h,
      lnxg, lnxb, lnhg, lnhb, Wh2mod, bh2mod, Wmod2h, bmod2h,
      alpha, tauU, out);
}

// Round 8
// 270.346 us; speedup vs baseline: 1.4917x; 1.4917x over previous
//
#include <hip/hip_runtime.h>

// Problem dims
#define H_  256
#define I_  128
#define R_  32
#define B_  16
#define T_  48
#define H3_ 768

// d_out float offsets: (v, h, dU, trace_e, trace_E, outs, mods)
#define OFF_V    0
#define OFF_H    4096
#define OFF_DU   8192
#define OFF_TE   1056768
#define OFF_TT   1060864
#define OFF_OUTS 2109440
#define OFF_MODS 2306048

#define BAR_STRIDE 32          // ints; 128B between group counter regions

typedef unsigned long long u64;

// Module-static scratch (allocated at .so load; zero-init).
__device__ __align__(16) float g_wx[T_*B_*H3_];   // LN(x@Wx^T+b) precomputed
// Packed (tag<<32 | float_bits) mailboxes: tag==t means "value for step t".
__device__ __align__(16) u64 g_whp[2*B_*H3_];     // double-buffered h@Wh^T (+bias)
__device__ __align__(16) u64 g_plp[2*B_*H_];      // double-buffered plastic
__device__ int g_bar[B_*BAR_STRIDE];              // init barrier counter; self-reset
__device__ int g_done[B_*BAR_STRIDE];

__device__ __forceinline__ float sigmf(float v){ return 1.0f/(1.0f+__expf(-v)); }

// ---- DPP full-wave sum (VALU path, ~10cy/hop vs ~35cy ds_swizzle). Result in lane 63.
#define DPPADD(x, ctrl, rmask) \
  x += __int_as_float(__builtin_amdgcn_update_dpp(0, __float_as_int(x), ctrl, rmask, 0xf, false))
__device__ __forceinline__ float wred(float x){
  DPPADD(x, 0x111, 0xf);   // row_shr:1
  DPPADD(x, 0x112, 0xf);   // row_shr:2
  DPPADD(x, 0x114, 0xf);   // row_shr:4
  DPPADD(x, 0x118, 0xf);   // row_shr:8
  DPPADD(x, 0x142, 0xa);   // row_bcast:15 -> rows 1,3
  DPPADD(x, 0x143, 0xc);   // row_bcast:31 -> rows 2,3
  return x;
}

// Producer side: agent-scope store (PROVEN visible at the coherence point).
__device__ __forceinline__ void pstore(u64* p, int tag, float v){
  u64 u = ((u64)(unsigned)tag << 32) | (u64)__float_as_uint(v);
  __hip_atomic_store(p, u, __ATOMIC_RELAXED, __HIP_MEMORY_SCOPE_AGENT);
}
// Consumer side, guaranteed-progress round: agent-scope load.
__device__ __forceinline__ u64 pload(const u64* p){
  return __hip_atomic_load((u64*)p, __ATOMIC_RELAXED, __HIP_MEMORY_SCOPE_AGENT);
}
// Consumer side, opportunistic round: sc0 (L1-bypass, L2-serveable) loads.
// Stale data is HARMLESS: tag mismatch -> retry. Liveness comes from the
// interleaved agent rounds, so this can never hang regardless of sc0 semantics.
__device__ __forceinline__ void pload4_l2(const u64* p0, const u64* p1,
                                          const u64* p2, const u64* p3,
                                          u64& u0, u64& u1, u64& u2, u64& u3){
  asm volatile(
    "global_load_dwordx2 %0, %4, off sc0\n\t"
    "global_load_dwordx2 %1, %5, off sc0\n\t"
    "global_load_dwordx2 %2, %6, off sc0\n\t"
    "global_load_dwordx2 %3, %7, off sc0\n\t"
    "s_waitcnt vmcnt(0)"
    : "=&v"(u0), "=&v"(u1), "=&v"(u2), "=&v"(u3)
    : "v"(p0), "v"(p1), "v"(p2), "v"(p3)
    : "memory");
}

// Full barrier (init only): publishes plain g_wx stores via cache-wide fence.
__device__ __forceinline__ void groupbar_full(int* ctr, int target){
  __syncthreads();
  if (threadIdx.x == 0){
    __threadfence();                   // release: flush plain writes
    __hip_atomic_fetch_add(ctr, 1, __ATOMIC_RELAXED, __HIP_MEMORY_SCOPE_AGENT);
    while (__hip_atomic_load(ctr, __ATOMIC_RELAXED, __HIP_MEMORY_SCOPE_AGENT) < target)
      __builtin_amdgcn_s_sleep(1);
    __threadfence();                   // acquire: inv
  }
  __syncthreads();
}

__global__ __launch_bounds__(256, 1) void sgru_kernel(
    const float* __restrict__ x,     const float* __restrict__ h0,
    const float* __restrict__ v0,    const float* __restrict__ dU0,
    const float* __restrict__ te0,   const float* __restrict__ tE0,
    const float* __restrict__ Wx2h,  const float* __restrict__ bx2h,
    const float* __restrict__ Wh2h,  const float* __restrict__ bh2h,
    const float* __restrict__ lnxg,  const float* __restrict__ lnxb,
    const float* __restrict__ lnhg,  const float* __restrict__ lnhb,
    const float* __restrict__ Wh2mod,const float* __restrict__ bh2mod,
    const float* __restrict__ Wmod2h,const float* __restrict__ bmod2h,
    const float* __restrict__ alpha, const float* __restrict__ tauU,
    float* __restrict__ out)
{
  const int tid  = threadIdx.x;
  const int g    = blockIdx.x;
  // XCD-local grouping HEURISTIC (round-robin dispatch: XCD = g%8): group b's
  // 16 blocks all share g%8 -> likely same XCD -> sc0 poll rounds can hit L2.
  // Correctness does NOT depend on this (agent rounds guarantee progress).
  const int b    = (g & 7) + 8*(g >> 7);
  const int c    = (g >> 3) & 15;
  const int lane = tid & 63;
  const int wv   = tid >> 6;

  __shared__ __align__(16) float hn_s[H_], ten_s[H_];
  __shared__ __align__(16) float xst_s[3*I_];          // init-only x staging
  __shared__ __align__(16) float lnhg_s[H3_], lnhb_s[H3_];
  // Wh2h rows, swizzled so per-u ds_read_b128 is lane-contiguous (conflict-free).
  __shared__ __align__(16) float wrow_s[48*256];
  __shared__ float mod_s[R_];
  __shared__ float red_s[8];

  float* ws_wx = g_wx;
  int*   ctr   = g_bar  + b*BAR_STRIDE;
  int*   dctr  = g_done + b*BAR_STRIDE;

  const float sp_a    = log1pf(__expf(alpha[0]));   // softplus(alpha)
  const float inv_spa = 1.0f / sp_a;
  const float tau     = sigmf(tauU[0]);

  // ---------------- init: states + weight staging ----------------
  float h_r  = h0[b*H_+tid];
  float v_r  = v0[b*H_+tid];
  float te_r = te0[b*H_+tid];
  hn_s[tid] = h_r;                      // staging for init dots
  for (int idx = tid; idx < 48*64; idx += 256){
    int d = idx >> 6, j = idx & 63;
    float4 w4 = ((const float4*)(Wh2h + ((size_t)(c*48 + d))*H_))[j];
    ((float4*)wrow_s)[(d>>4)*1024 + (j>>2)*64 + (d&15)*4 + (j&3)] = w4;
  }
  for (int idx = tid; idx < H3_; idx += 256){
    lnhg_s[idx] = lnhg[idx];
    lnhb_s[idx] = lnhb[idx];
  }
  float4 upR[4], loR[4];                // precomputed clip bounds (loop-invariant)
  float4 duR[4], tER[4];                // PERSISTENT dU/tE fragments (my 16 rows)
  #pragma unroll
  for (int rr = 0; rr < 4; rr++){
    int i = c*16 + rr*4 + wv;
    float4 w = ((const float4*)(Wh2h + ((size_t)(2*H_ + i))*H_))[lane];
    upR[rr].x =  fmaxf(1.0f - w.x, 0.0f)*inv_spa;
    upR[rr].y =  fmaxf(1.0f - w.y, 0.0f)*inv_spa;
    upR[rr].z =  fmaxf(1.0f - w.z, 0.0f)*inv_spa;
    upR[rr].w =  fmaxf(1.0f - w.w, 0.0f)*inv_spa;
    loR[rr].x = -fmaxf(1.0f + w.x, 0.0f)*inv_spa;
    loR[rr].y = -fmaxf(1.0f + w.y, 0.0f)*inv_spa;
    loR[rr].z = -fmaxf(1.0f + w.z, 0.0f)*inv_spa;
    loR[rr].w = -fmaxf(1.0f + w.w, 0.0f)*inv_spa;
    size_t rowo = ((size_t)(b*H_ + i))*H_;
    duR[rr] = ((const float4*)(dU0 + rowo))[lane];
    tER[rr] = ((const float4*)(tE0 + rowo))[lane];
  }
  const int mk = tid >> 3;              // mod row 0..31
  const int l8 = tid & 7;
  float4 wm[8];
  #pragma unroll
  for (int j = 0; j < 8; j++)
    wm[j] = ((const float4*)(Wh2mod + (size_t)mk*H_))[j*8 + l8];
  const float bh2m = bh2mod[mk];
  const float wmA = Wmod2h[lane & 31];
  const float wmB = Wmod2h[R_ + (lane & 31)];
  const float bm0 = bmod2h[0], bm1 = bmod2h[1];
  float bh2h_reg = 0.f;
  if (tid < 192) bh2h_reg = bh2h[c*48 + (tid>>2)];
  __syncthreads();

  // ---- init: Wx_ln rows t = c*3+q for batch b (carry-independent)
  {
    float* xr = xst_s;   // [3][128]
    for (int idx = tid; idx < 3*I_; idx += 256){
      int q = idx >> 7, e = idx & 127;
      xr[q*I_ + e] = x[((size_t)((c*3+q)*B_ + b))*I_ + e];
    }
    __syncthreads();
    float acc[3][3];
    #pragma unroll
    for (int k = 0; k < 3; k++){
      acc[k][0]=0.f; acc[k][1]=0.f; acc[k][2]=0.f;
      int f = tid + 256*k;
      const float4* wr = (const float4*)(Wx2h + (size_t)f*I_);
      for (int e4 = 0; e4 < I_/4; e4++){
        float4 w4 = wr[e4];
        int e = e4*4;
        #pragma unroll
        for (int q = 0; q < 3; q++){
          float t0 = fmaf(w4.x, xr[q*I_+e],   acc[k][q]);
          t0       = fmaf(w4.y, xr[q*I_+e+1], t0);
          t0       = fmaf(w4.z, xr[q*I_+e+2], t0);
          acc[k][q]= fmaf(w4.w, xr[q*I_+e+3], t0);
        }
      }
      float bf = bx2h[f];
      acc[k][0]+=bf; acc[k][1]+=bf; acc[k][2]+=bf;
    }
    __syncthreads();
    for (int q = 0; q < 3; q++){
      float s1 = acc[0][q]+acc[1][q]+acc[2][q];
      float s2 = acc[0][q]*acc[0][q]+acc[1][q]*acc[1][q]+acc[2][q]*acc[2][q];
      #pragma unroll
      for (int off=32; off>0; off>>=1){ s1 += __shfl_xor(s1,off); s2 += __shfl_xor(s2,off); }
      if (lane==0){ red_s[wv]=s1; red_s[4+wv]=s2; }
      __syncthreads();
      s1 = red_s[0]+red_s[1]+red_s[2]+red_s[3];
      s2 = red_s[4]+red_s[5]+red_s[6]+red_s[7];
      __syncthreads();
      float mu  = s1*(1.0f/768.0f);
      float var = s2*(1.0f/768.0f) - mu*mu;
      float rs  = rsqrtf(var + 1e-5f);
      float* dst = ws_wx + ((size_t)((c*3+q)*B_ + b))*H3_;
      #pragma unroll
      for (int k = 0; k < 3; k++){
        int f = tid + 256*k;
        dst[f] = (acc[k][q]-mu)*rs*lnxg[f] + lnxb[f];
      }
    }
  }

  // ---- init: plastic_0 (tag 0) + Wh_raw_0 (tag 0), slot 0
  {
    const float4* h4 = (const float4*)hn_s;
    float4 hj = h4[lane];
    float a[4];
    #pragma unroll
    for (int rr = 0; rr < 4; rr++){
      float4 du = duR[rr];
      a[rr] = du.x*hj.x + du.y*hj.y + du.z*hj.z + du.w*hj.w;
    }
    #pragma unroll
    for (int off=32; off>0; off>>=1){
      a[0] += __shfl_xor(a[0],off); a[1] += __shfl_xor(a[1],off);
      a[2] += __shfl_xor(a[2],off); a[3] += __shfl_xor(a[3],off);
    }
    if (lane==0){
      #pragma unroll
      for (int rr = 0; rr < 4; rr++)
        pstore(&g_plp[b*H_ + c*16 + rr*4 + wv], 0, sp_a*a[rr]);
    }
    if (tid < 192){
      const int w  = tid >> 6;          // wave 0..2
      const int l4 = lane & 3;
      const float4* wb  = ((const float4*)wrow_s) + w*1024;
      const float4* hh4 = (const float4*)hn_s;
      float ax=0.f, ay=0.f, az=0.f, aw=0.f;
      #pragma unroll
      for (int u = 0; u < 16; u++){
        float4 w4 = wb[u*64 + lane];          // lane-contiguous: conflict-free
        float4 hv = hh4[u*4 + l4];            // 4-addr broadcast
        ax = fmaf(w4.x,hv.x,ax); ay = fmaf(w4.y,hv.y,ay);
        az = fmaf(w4.z,hv.z,az); aw = fmaf(w4.w,hv.w,aw);
      }
      float acc = (ax+ay)+(az+aw);
      acc += __shfl_xor(acc,1);
      acc += __shfl_xor(acc,2);
      if (l4==0) pstore(&g_whp[b*H3_ + c*48 + w*16 + (lane>>2)], 0, acc + bh2h_reg);
    }
  }
  groupbar_full(ctr, 16);

  // ---------------- scan: tag-fused mailboxes, 3 barriers/step ----------------
  for (int t = 0; t < T_; t++){
    const int p  = t & 1;
    const int pn = p ^ 1;

    const float* wxr = ws_wx + ((size_t)(t*B_ + b))*H3_;
    float wx0 = wxr[tid], wx1 = wxr[tid+256], wx2 = wxr[tid+512];

    // ---- poll: value+tag in one load; alternate sc0 (fast, opportunistic)
    //      and agent (guaranteed-progress) rounds. Hang-proof by construction.
    const u64* whp = g_whp + p*(B_*H3_) + b*H3_;
    const u64* plp = g_plp + p*(B_*H_)  + b*H_;
    u64 u0, u1, u2, u3;
    int round = 0;
    for(;;){
      if ((round & 1) == 0){
        pload4_l2(whp+tid, whp+tid+256, whp+tid+512, plp+tid, u0, u1, u2, u3);
      } else {
        u0 = pload(whp + tid);
        u1 = pload(whp + tid + 256);
        u2 = pload(whp + tid + 512);
        u3 = pload(plp + tid);
      }
      bool ok = ((int)(u0>>32)==t) && ((int)(u1>>32)==t) &&
                ((int)(u2>>32)==t) && ((int)(u3>>32)==t);
      if (__all(ok)) break;
      round++;
    }
    float wh0 = __uint_as_float((unsigned)u0);
    float wh1 = __uint_as_float((unsigned)u1);
    float wh2 = __uint_as_float((unsigned)u2) + __uint_as_float((unsigned)u3);

    // ---- LN + gates (state h/v/te in registers; DPP reduce on serial path)
    float hn, ten;
    {
      float s1 = wh0+wh1+wh2;
      float s2 = fmaf(wh0,wh0, fmaf(wh1,wh1, wh2*wh2));
      s1 = wred(s1); s2 = wred(s2);
      if (lane==63){ red_s[wv]=s1; red_s[4+wv]=s2; }
      __syncthreads();                                   // sync #1
      s1 = red_s[0]+red_s[1]+red_s[2]+red_s[3];
      s2 = red_s[4]+red_s[5]+red_s[6]+red_s[7];
      float mu  = s1*(1.0f/768.0f);
      float var = s2*(1.0f/768.0f) - mu*mu;
      float rs  = rsqrtf(var + 1e-5f);
      float pre0 = wx0 + (wh0-mu)*rs*lnhg_s[tid]     + lnhb_s[tid];
      float pre1 = wx1 + (wh1-mu)*rs*lnhg_s[tid+256] + lnhb_s[tid+256];
      float pre2 = wx2 + (wh2-mu)*rs*lnhg_s[tid+512] + lnhb_s[tid+512];
      float z   = sigmf(pre0);
      float r   = sigmf(pre1);
      float vn  = fmaf(z, pre2 - v_r, v_r);     // (1-z)v + z dv
      hn  = fmaxf(vn, 0.0f);
      ten = fmaf(r, h_r - te_r, te_r);          // (1-r)te + r h_old
      v_r = vn; h_r = hn; te_r = ten;
      hn_s[tid] = hn; ten_s[tid] = ten;
    }
    __syncthreads();                                     // sync #2

    // ---- hoisted U-phase LDS loads
    const float4* hn4 = (const float4*)hn_s;
    const float4* te4 = (const float4*)ten_s;
    float4 hj = hn4[lane];
    float4 tj = te4[lane];
    float hni[4], teni[4];
    #pragma unroll
    for (int rr = 0; rr < 4; rr++){
      int i = c*16 + rr*4 + wv;
      hni[rr]  = hn_s[i];
      teni[rr] = ten_s[i];
    }

    // ---- Wh(t+1): FIRST (publish as early as possible; R4-proven ordering)
    if (t < T_-1 && tid < 192){
      const int w  = tid >> 6;
      const int l4 = lane & 3;
      const float4* wb  = ((const float4*)wrow_s) + w*1024;
      float ax=0.f, ay=0.f, az=0.f, aw=0.f;
      #pragma unroll
      for (int u = 0; u < 16; u++){
        float4 w4 = wb[u*64 + lane];
        float4 hv = hn4[u*4 + l4];
        ax = fmaf(w4.x,hv.x,ax); ay = fmaf(w4.y,hv.y,ay);
        az = fmaf(w4.z,hv.z,az); aw = fmaf(w4.w,hv.w,aw);
      }
      float acc = (ax+ay)+(az+aw);
      acc += __shfl_xor(acc,1);
      acc += __shfl_xor(acc,2);
      if (l4==0) pstore(&g_whp[pn*(B_*H3_) + b*H3_ + c*48 + w*16 + (lane>>2)],
                        t+1, acc + bh2h_reg);
    }

    // ---- mod dot (LDS only; 4-way accumulators)
    {
      float mx=0.f, my=0.f, mz=0.f, mw=0.f;
      #pragma unroll
      for (int j = 0; j < 8; j++){
        float4 hv = hn4[j*8 + l8];
        float4 w4 = wm[j];
        mx = fmaf(w4.x,hv.x,mx); my = fmaf(w4.y,hv.y,my);
        mz = fmaf(w4.z,hv.z,mz); mw = fmaf(w4.w,hv.w,mw);
      }
      float acc = (mx+my)+(mz+mw);
      acc += __shfl_xor(acc,1); acc += __shfl_xor(acc,2); acc += __shfl_xor(acc,4);
      if (l8==0) mod_s[mk] = fmaxf(acc + bh2m, 0.0f);
    }
    __syncthreads();                                     // sync #3 (last of the step)

    // s/m redundantly per-lane
    float s_b, m_b;
    {
      float mv = mod_s[lane & 31];
      float p0 = mv*wmA, p1 = mv*wmB;
      #pragma unroll
      for (int off=16; off>0; off>>=1){ p0 += __shfl_xor(p0,off); p1 += __shfl_xor(p1,off); }
      s_b = sigmf(p0 + bm0);
      m_b = p1 + bm1;
    }

    // ---- U phase: register-resident tE/dU update; pl publish ASAP
    float pacc[4];
    #pragma unroll
    for (int rr = 0; rr < 4; rr++){
      float4 du = duR[rr];
      float4 tE = tER[rr];
      float4 up = upR[rr];
      float4 lo = loR[rr];
      float h_i = hni[rr], t_i = teni[rr];
      float4 nd, nt;
      float acc;
      { float o_ = h_i*tj.x - t_i*hj.x;
        float tn = fmaf(s_b, o_ - tE.x, tE.x);
        float dn = fmaf(tau, fmaf(m_b, tn, -du.x), du.x);
        dn = fminf(dn, up.x); dn = fmaxf(dn, lo.x);
        nt.x = tn; nd.x = dn; acc = dn*hj.x; }
      { float o_ = h_i*tj.y - t_i*hj.y;
        float tn = fmaf(s_b, o_ - tE.y, tE.y);
        float dn = fmaf(tau, fmaf(m_b, tn, -du.y), du.y);
        dn = fminf(dn, up.y); dn = fmaxf(dn, lo.y);
        nt.y = tn; nd.y = dn; acc = fmaf(dn, hj.y, acc); }
      { float o_ = h_i*tj.z - t_i*hj.z;
        float tn = fmaf(s_b, o_ - tE.z, tE.z);
        float dn = fmaf(tau, fmaf(m_b, tn, -du.z), du.z);
        dn = fminf(dn, up.z); dn = fmaxf(dn, lo.z);
        nt.z = tn; nd.z = dn; acc = fmaf(dn, hj.z, acc); }
      { float o_ = h_i*tj.w - t_i*hj.w;
        float tn = fmaf(s_b, o_ - tE.w, tE.w);
        float dn = fmaf(tau, fmaf(m_b, tn, -du.w), du.w);
        dn = fminf(dn, up.w); dn = fmaxf(dn, lo.w);
        nt.w = tn; nd.w = dn; acc = fmaf(dn, hj.w, acc); }
      duR[rr] = nd;
      tER[rr] = nt;
      pacc[rr] = acc;
    }
    #pragma unroll
    for (int off=32; off>0; off>>=1){
      pacc[0] += __shfl_xor(pacc[0],off); pacc[1] += __shfl_xor(pacc[1],off);
      pacc[2] += __shfl_xor(pacc[2],off); pacc[3] += __shfl_xor(pacc[3],off);
    }
    if (t < T_-1 && lane==0){
      u64* pd = g_plp + pn*(B_*H_) + b*H_ + c*16 + wv;
      pstore(pd + 0,  t+1, sp_a*pacc[0]);
      pstore(pd + 4,  t+1, sp_a*pacc[1]);
      pstore(pd + 8,  t+1, sp_a*pacc[2]);
      pstore(pd + 12, t+1, sp_a*pacc[3]);
    }

    // ---- outputs: AFTER publishes (off the inter-block serial path)
    if (tid < 16) out[OFF_OUTS + ((size_t)(t*B_+b))*H_ + c*16 + tid] = hn_s[c*16 + tid];
    if (tid < 2)  out[OFF_MODS + ((size_t)(t*B_+b))*R_ + c*2 + tid]  = mod_s[c*2 + tid];
    if (t == T_-1){
      #pragma unroll
      for (int rr = 0; rr < 4; rr++){
        int i = c*16 + rr*4 + wv;
        size_t rowo = ((size_t)(b*H_ + i))*H_;
        ((float4*)(out + OFF_DU + rowo))[lane] = duR[rr];
        ((float4*)(out + OFF_TT + rowo))[lane] = tER[rr];
      }
      if (c == 0){
        out[OFF_V  + b*H_ + tid] = v_r;
        out[OFF_H  + b*H_ + tid] = h_r;
        out[OFF_TE + b*H_ + tid] = te_r;
      }
    }
    // no end-of-step barrier: next iteration's poll enforces all ordering
  }

  // ---- self-reset of group counters for the next launch.
  __syncthreads();
  if (threadIdx.x == 0){
    int d = __hip_atomic_fetch_add(dctr, 1, __ATOMIC_RELAXED, __HIP_MEMORY_SCOPE_AGENT);
    if (d == 15){
      __hip_atomic_store(ctr,  0, __ATOMIC_RELAXED, __HIP_MEMORY_SCOPE_AGENT);
      __hip_atomic_store(dctr, 0, __ATOMIC_RELAXED, __HIP_MEMORY_SCOPE_AGENT);
    }
  }
}

extern "C" void kernel_launch(void* const* d_in, const int* in_sizes, int n_in,
                              void* d_out, int out_size, void* d_ws, size_t ws_size,
                              hipStream_t stream)
{
  const float* x      = (const float*)d_in[0];
  const float* h0     = (const float*)d_in[1];
  const float* v0     = (const float*)d_in[2];
  const float* dU0    = (const float*)d_in[3];
  const float* te0    = (const float*)d_in[4];
  const float* tE0    = (const float*)d_in[5];
  const float* Wx2h   = (const float*)d_in[6];
  const float* bx2h   = (const float*)d_in[7];
  const float* Wh2h   = (const float*)d_in[8];
  const float* bh2h   = (const float*)d_in[9];
  const float* lnxg   = (const float*)d_in[10];
  const float* lnxb   = (const float*)d_in[11];
  const float* lnhg   = (const float*)d_in[12];
  const float* lnhb   = (const float*)d_in[13];
  const float* Wh2mod = (const float*)d_in[14];
  const float* bh2mod = (const float*)d_in[15];
  const float* Wmod2h = (const float*)d_in[16];
  const float* bmod2h = (const float*)d_in[17];
  const float* alpha  = (const float*)d_in[18];
  const float* tauU   = (const float*)d_in[19];
  float* out = (float*)d_out;

  sgru_kernel<<<dim3(256), dim3(256), 0, stream>>>(
      x, h0, v0, dU0, te0, tE0, Wx2h, bx2h, Wh2h, bh2h,
      lnxg, lnxb, lnhg, lnhb, Wh2mod, bh2mod, Wmod2h, bmod2h,
      alpha, tauU, out);
}

// Round 9
// 264.319 us; speedup vs baseline: 1.5257x; 1.0228x over previous
//
#include <hip/hip_runtime.h>

// Problem dims
#define H_  256
#define I_  128
#define R_  32
#define B_  16
#define T_  48
#define H3_ 768

// d_out float offsets: (v, h, dU, trace_e, trace_E, outs, mods)
#define OFF_V    0
#define OFF_H    4096
#define OFF_DU   8192
#define OFF_TE   1056768
#define OFF_TT   1060864
#define OFF_OUTS 2109440
#define OFF_MODS 2306048

#define BAR_STRIDE 32          // ints; 128B between group counter regions

typedef unsigned long long u64;

// Module-static scratch (allocated at .so load; zero-init).
__device__ __align__(16) float g_wx[T_*B_*H3_];   // LN(x@Wx^T+b) precomputed
// Packed (tag<<32 | float_bits) mailboxes: tag==t means "value for step t".
__device__ __align__(16) u64 g_whp[2*B_*H3_];     // double-buffered h@Wh^T (+bias)
__device__ __align__(16) u64 g_plp[2*B_*H_];      // double-buffered plastic
__device__ int g_bar[B_*BAR_STRIDE];              // init barrier counter; self-reset
__device__ int g_done[B_*BAR_STRIDE];

__device__ __forceinline__ float sigmf(float v){ return 1.0f/(1.0f+__expf(-v)); }

// ---- DPP reductions (VALU path, ~10cy/hop vs ~35cy ds_swizzle) ----
#define DPPADD(x, ctrl, rmask) \
  x += __int_as_float(__builtin_amdgcn_update_dpp(0, __float_as_int(x), ctrl, rmask, 0xf, false))
// Full 64-lane sum; result valid in lane 63 ONLY (partial row masks).
__device__ __forceinline__ float wred(float x){
  DPPADD(x, 0x111, 0xf);   // row_shr:1
  DPPADD(x, 0x112, 0xf);   // row_shr:2
  DPPADD(x, 0x114, 0xf);   // row_shr:4
  DPPADD(x, 0x118, 0xf);   // row_shr:8
  DPPADD(x, 0x142, 0xa);   // row_bcast:15 -> rows 1,3
  DPPADD(x, 0x143, 0xc);   // row_bcast:31 -> rows 2,3
  return x;
}
// 8-lane aligned-group sum; valid at lanes with (lane&7)==7.
__device__ __forceinline__ float red8(float x){
  DPPADD(x, 0x111, 0xf); DPPADD(x, 0x112, 0xf); DPPADD(x, 0x114, 0xf);
  return x;
}
// 4-lane aligned-group sum; valid at lanes with (lane&3)==3.
__device__ __forceinline__ float red4(float x){
  DPPADD(x, 0x111, 0xf); DPPADD(x, 0x112, 0xf);
  return x;
}
__device__ __forceinline__ float bcast63(float x){
  return __int_as_float(__builtin_amdgcn_readlane(__float_as_int(x), 63));
}

// Producer side: agent-scope store (PROVEN visible at the coherence point).
__device__ __forceinline__ void pstore(u64* p, int tag, float v){
  u64 u = ((u64)(unsigned)tag << 32) | (u64)__float_as_uint(v);
  __hip_atomic_store(p, u, __ATOMIC_RELAXED, __HIP_MEMORY_SCOPE_AGENT);
}
// Consumer side, guaranteed-progress round: agent-scope load.
__device__ __forceinline__ u64 pload(const u64* p){
  return __hip_atomic_load((u64*)p, __ATOMIC_RELAXED, __HIP_MEMORY_SCOPE_AGENT);
}
// Consumer side, opportunistic round: sc0 (L1-bypass, L2-serveable) loads.
// Stale data is HARMLESS: tag mismatch -> retry. Liveness from agent rounds.
__device__ __forceinline__ void pload4_l2(const u64* p0, const u64* p1,
                                          const u64* p2, const u64* p3,
                                          u64& u0, u64& u1, u64& u2, u64& u3){
  asm volatile(
    "global_load_dwordx2 %0, %4, off sc0\n\t"
    "global_load_dwordx2 %1, %5, off sc0\n\t"
    "global_load_dwordx2 %2, %6, off sc0\n\t"
    "global_load_dwordx2 %3, %7, off sc0\n\t"
    "s_waitcnt vmcnt(0)"
    : "=&v"(u0), "=&v"(u1), "=&v"(u2), "=&v"(u3)
    : "v"(p0), "v"(p1), "v"(p2), "v"(p3)
    : "memory");
}

// Full barrier (init only): publishes plain g_wx stores via cache-wide fence.
__device__ __forceinline__ void groupbar_full(int* ctr, int target){
  __syncthreads();
  if (threadIdx.x == 0){
    __threadfence();                   // release: flush plain writes
    __hip_atomic_fetch_add(ctr, 1, __ATOMIC_RELAXED, __HIP_MEMORY_SCOPE_AGENT);
    while (__hip_atomic_load(ctr, __ATOMIC_RELAXED, __HIP_MEMORY_SCOPE_AGENT) < target)
      __builtin_amdgcn_s_sleep(1);
    __threadfence();                   // acquire: inv
  }
  __syncthreads();
}

__global__ __launch_bounds__(256, 1) void sgru_kernel(
    const float* __restrict__ x,     const float* __restrict__ h0,
    const float* __restrict__ v0,    const float* __restrict__ dU0,
    const float* __restrict__ te0,   const float* __restrict__ tE0,
    const float* __restrict__ Wx2h,  const float* __restrict__ bx2h,
    const float* __restrict__ Wh2h,  const float* __restrict__ bh2h,
    const float* __restrict__ lnxg,  const float* __restrict__ lnxb,
    const float* __restrict__ lnhg,  const float* __restrict__ lnhb,
    const float* __restrict__ Wh2mod,const float* __restrict__ bh2mod,
    const float* __restrict__ Wmod2h,const float* __restrict__ bmod2h,
    const float* __restrict__ alpha, const float* __restrict__ tauU,
    float* __restrict__ out)
{
  const int tid  = threadIdx.x;
  const int g    = blockIdx.x;
  // XCD-local grouping HEURISTIC (round-robin dispatch: XCD = g%8): group b's
  // 16 blocks all share g%8 -> likely same XCD -> sc0 poll rounds hit L2.
  // Correctness does NOT depend on this (agent rounds guarantee progress).
  const int b    = (g & 7) + 8*(g >> 7);
  const int c    = (g >> 3) & 15;
  const int lane = tid & 63;
  const int wv   = tid >> 6;

  __shared__ __align__(16) float hn_s[H_], ten_s[H_];
  __shared__ __align__(16) float xst_s[3*I_];          // init-only x staging
  // Wh2h rows, swizzled so per-u ds_read_b128 is lane-contiguous (conflict-free).
  __shared__ __align__(16) float wrow_s[48*256];
  __shared__ float mod_s[R_];
  __shared__ float red_s[8];

  float* ws_wx = g_wx;
  int*   ctr   = g_bar  + b*BAR_STRIDE;
  int*   dctr  = g_done + b*BAR_STRIDE;

  const float sp_a    = log1pf(__expf(alpha[0]));   // softplus(alpha)
  const float inv_spa = 1.0f / sp_a;
  const float tau     = sigmf(tauU[0]);

  // ---------------- init: states + weight staging ----------------
  float h_r  = h0[b*H_+tid];
  float v_r  = v0[b*H_+tid];
  float te_r = te0[b*H_+tid];
  hn_s[tid] = h_r;                      // staging for init dots
  for (int idx = tid; idx < 48*64; idx += 256){
    int d = idx >> 6, j = idx & 63;
    float4 w4 = ((const float4*)(Wh2h + ((size_t)(c*48 + d))*H_))[j];
    ((float4*)wrow_s)[(d>>4)*1024 + (j>>2)*64 + (d&15)*4 + (j&3)] = w4;
  }
  // LN(h) gamma/beta in REGISTERS (per-thread constants; off LDS path)
  const float lg0 = lnhg[tid], lg1 = lnhg[tid+256], lg2 = lnhg[tid+512];
  const float lb0 = lnhb[tid], lb1 = lnhb[tid+256], lb2 = lnhb[tid+512];
  float4 upR[4], loR[4];                // precomputed clip bounds (loop-invariant)
  float4 duR[4], tER[4];                // PERSISTENT dU/tE fragments (my 16 rows)
  #pragma unroll
  for (int rr = 0; rr < 4; rr++){
    int i = c*16 + rr*4 + wv;
    float4 w = ((const float4*)(Wh2h + ((size_t)(2*H_ + i))*H_))[lane];
    upR[rr].x =  fmaxf(1.0f - w.x, 0.0f)*inv_spa;
    upR[rr].y =  fmaxf(1.0f - w.y, 0.0f)*inv_spa;
    upR[rr].z =  fmaxf(1.0f - w.z, 0.0f)*inv_spa;
    upR[rr].w =  fmaxf(1.0f - w.w, 0.0f)*inv_spa;
    loR[rr].x = -fmaxf(1.0f + w.x, 0.0f)*inv_spa;
    loR[rr].y = -fmaxf(1.0f + w.y, 0.0f)*inv_spa;
    loR[rr].z = -fmaxf(1.0f + w.z, 0.0f)*inv_spa;
    loR[rr].w = -fmaxf(1.0f + w.w, 0.0f)*inv_spa;
    size_t rowo = ((size_t)(b*H_ + i))*H_;
    duR[rr] = ((const float4*)(dU0 + rowo))[lane];
    tER[rr] = ((const float4*)(tE0 + rowo))[lane];
  }
  const int mk = tid >> 3;              // mod row 0..31
  const int l8 = tid & 7;
  float4 wm[8];
  #pragma unroll
  for (int j = 0; j < 8; j++)
    wm[j] = ((const float4*)(Wh2mod + (size_t)mk*H_))[j*8 + l8];
  const float bh2m = bh2mod[mk];
  const float wmA = Wmod2h[lane & 31];
  const float wmB = Wmod2h[R_ + (lane & 31)];
  const float bm0 = bmod2h[0], bm1 = bmod2h[1];
  float bh2h_reg = 0.f;
  if (tid < 192) bh2h_reg = bh2h[c*48 + (tid>>2)];
  __syncthreads();

  // ---- init: Wx_ln rows t = c*3+q for batch b (carry-independent)
  {
    float* xr = xst_s;   // [3][128]
    for (int idx = tid; idx < 3*I_; idx += 256){
      int q = idx >> 7, e = idx & 127;
      xr[q*I_ + e] = x[((size_t)((c*3+q)*B_ + b))*I_ + e];
    }
    __syncthreads();
    float acc[3][3];
    #pragma unroll
    for (int k = 0; k < 3; k++){
      acc[k][0]=0.f; acc[k][1]=0.f; acc[k][2]=0.f;
      int f = tid + 256*k;
      const float4* wr = (const float4*)(Wx2h + (size_t)f*I_);
      for (int e4 = 0; e4 < I_/4; e4++){
        float4 w4 = wr[e4];
        int e = e4*4;
        #pragma unroll
        for (int q = 0; q < 3; q++){
          float t0 = fmaf(w4.x, xr[q*I_+e],   acc[k][q]);
          t0       = fmaf(w4.y, xr[q*I_+e+1], t0);
          t0       = fmaf(w4.z, xr[q*I_+e+2], t0);
          acc[k][q]= fmaf(w4.w, xr[q*I_+e+3], t0);
        }
      }
      float bf = bx2h[f];
      acc[k][0]+=bf; acc[k][1]+=bf; acc[k][2]+=bf;
    }
    __syncthreads();
    for (int q = 0; q < 3; q++){
      float s1 = acc[0][q]+acc[1][q]+acc[2][q];
      float s2 = acc[0][q]*acc[0][q]+acc[1][q]*acc[1][q]+acc[2][q]*acc[2][q];
      #pragma unroll
      for (int off=32; off>0; off>>=1){ s1 += __shfl_xor(s1,off); s2 += __shfl_xor(s2,off); }
      if (lane==0){ red_s[wv]=s1; red_s[4+wv]=s2; }
      __syncthreads();
      s1 = red_s[0]+red_s[1]+red_s[2]+red_s[3];
      s2 = red_s[4]+red_s[5]+red_s[6]+red_s[7];
      __syncthreads();
      float mu  = s1*(1.0f/768.0f);
      float var = s2*(1.0f/768.0f) - mu*mu;
      float rs  = rsqrtf(var + 1e-5f);
      float* dst = ws_wx + ((size_t)((c*3+q)*B_ + b))*H3_;
      #pragma unroll
      for (int k = 0; k < 3; k++){
        int f = tid + 256*k;
        dst[f] = (acc[k][q]-mu)*rs*lnxg[f] + lnxb[f];
      }
    }
  }

  // ---- init: plastic_0 (tag 0) + Wh_raw_0 (tag 0), slot 0
  {
    const float4* h4 = (const float4*)hn_s;
    float4 hj = h4[lane];
    float a[4];
    #pragma unroll
    for (int rr = 0; rr < 4; rr++){
      float4 du = duR[rr];
      a[rr] = du.x*hj.x + du.y*hj.y + du.z*hj.z + du.w*hj.w;
    }
    #pragma unroll
    for (int off=32; off>0; off>>=1){
      a[0] += __shfl_xor(a[0],off); a[1] += __shfl_xor(a[1],off);
      a[2] += __shfl_xor(a[2],off); a[3] += __shfl_xor(a[3],off);
    }
    if (lane==0){
      #pragma unroll
      for (int rr = 0; rr < 4; rr++)
        pstore(&g_plp[b*H_ + c*16 + rr*4 + wv], 0, sp_a*a[rr]);
    }
    if (tid < 192){
      const int w  = tid >> 6;          // wave 0..2
      const int l4 = lane & 3;
      const float4* wb  = ((const float4*)wrow_s) + w*1024;
      const float4* hh4 = (const float4*)hn_s;
      float ax=0.f, ay=0.f, az=0.f, aw=0.f;
      #pragma unroll
      for (int u = 0; u < 16; u++){
        float4 w4 = wb[u*64 + lane];          // lane-contiguous: conflict-free
        float4 hv = hh4[u*4 + l4];            // 4-addr broadcast
        ax = fmaf(w4.x,hv.x,ax); ay = fmaf(w4.y,hv.y,ay);
        az = fmaf(w4.z,hv.z,az); aw = fmaf(w4.w,hv.w,aw);
      }
      float acc = (ax+ay)+(az+aw);
      acc += __shfl_xor(acc,1);
      acc += __shfl_xor(acc,2);
      if (l4==0) pstore(&g_whp[b*H3_ + c*48 + w*16 + (lane>>2)], 0, acc + bh2h_reg);
    }
  }
  groupbar_full(ctr, 16);

  // ---------------- scan: tag-fused mailboxes, 3 barriers/step ----------------
  for (int t = 0; t < T_; t++){
    const int p  = t & 1;
    const int pn = p ^ 1;

    const float* wxr = ws_wx + ((size_t)(t*B_ + b))*H3_;
    float wx0 = wxr[tid], wx1 = wxr[tid+256], wx2 = wxr[tid+512];

    // ---- poll: value+tag in one load; alternate sc0 / agent rounds.
    const u64* whp = g_whp + p*(B_*H3_) + b*H3_;
    const u64* plp = g_plp + p*(B_*H_)  + b*H_;
    u64 u0, u1, u2, u3;
    int round = 0;
    for(;;){
      if ((round & 1) == 0){
        pload4_l2(whp+tid, whp+tid+256, whp+tid+512, plp+tid, u0, u1, u2, u3);
      } else {
        u0 = pload(whp + tid);
        u1 = pload(whp + tid + 256);
        u2 = pload(whp + tid + 512);
        u3 = pload(plp + tid);
      }
      bool ok = ((int)(u0>>32)==t) && ((int)(u1>>32)==t) &&
                ((int)(u2>>32)==t) && ((int)(u3>>32)==t);
      if (__all(ok)) break;
      round++;
    }
    float wh0 = __uint_as_float((unsigned)u0);
    float wh1 = __uint_as_float((unsigned)u1);
    float wh2 = __uint_as_float((unsigned)u2) + __uint_as_float((unsigned)u3);

    // ---- LN + gates (state h/v/te in registers; gamma/beta in registers)
    float hn, ten;
    {
      float s1 = wh0+wh1+wh2;
      float s2 = fmaf(wh0,wh0, fmaf(wh1,wh1, wh2*wh2));
      s1 = wred(s1); s2 = wred(s2);
      if (lane==63){ red_s[wv]=s1; red_s[4+wv]=s2; }
      __syncthreads();                                   // sync #1
      s1 = red_s[0]+red_s[1]+red_s[2]+red_s[3];
      s2 = red_s[4]+red_s[5]+red_s[6]+red_s[7];
      float mu  = s1*(1.0f/768.0f);
      float var = s2*(1.0f/768.0f) - mu*mu;
      float rs  = rsqrtf(var + 1e-5f);
      float pre0 = wx0 + (wh0-mu)*rs*lg0 + lb0;
      float pre1 = wx1 + (wh1-mu)*rs*lg1 + lb1;
      float pre2 = wx2 + (wh2-mu)*rs*lg2 + lb2;
      float z   = sigmf(pre0);
      float r   = sigmf(pre1);
      float vn  = fmaf(z, pre2 - v_r, v_r);     // (1-z)v + z dv
      hn  = fmaxf(vn, 0.0f);
      ten = fmaf(r, h_r - te_r, te_r);          // (1-r)te + r h_old
      v_r = vn; h_r = hn; te_r = ten;
      hn_s[tid] = hn; ten_s[tid] = ten;
    }
    __syncthreads();                                     // sync #2

    // ---- hoisted U-phase LDS loads (issue early; consumed later)
    const float4* hn4 = (const float4*)hn_s;
    const float4* te4 = (const float4*)ten_s;
    float4 hj = hn4[lane];
    float4 tj = te4[lane];
    float hni[4], teni[4];
    #pragma unroll
    for (int rr = 0; rr < 4; rr++){
      int i = c*16 + rr*4 + wv;
      hni[rr]  = hn_s[i];
      teni[rr] = ten_s[i];
    }

    // ---- mod dot FIRST (shortest path to sync#3 -> s/m -> U -> pl publish)
    {
      float mx=0.f, my=0.f, mz=0.f, mw=0.f;
      #pragma unroll
      for (int j = 0; j < 8; j++){
        float4 hv = hn4[j*8 + l8];
        float4 w4 = wm[j];
        mx = fmaf(w4.x,hv.x,mx); my = fmaf(w4.y,hv.y,my);
        mz = fmaf(w4.z,hv.z,mz); mw = fmaf(w4.w,hv.w,mw);
      }
      float acc = (mx+my)+(mz+mw);
      acc = red8(acc);
      if (l8==7) mod_s[mk] = fmaxf(acc + bh2m, 0.0f);
    }
    __syncthreads();                                     // sync #3 (last of step)

    // ---- s/m: per-lane redundant; mirrored halves => wred gives 2x sum
    float s_b, m_b;
    {
      float mv = mod_s[lane & 31];
      float p0 = mv*wmA, p1 = mv*wmB;
      p0 = wred(p0); p1 = wred(p1);
      s_b = sigmf(fmaf(0.5f, bcast63(p0), bm0));
      m_b = fmaf(0.5f, bcast63(p1), bm1);
    }

    // ---- U phase: register-resident tE/dU update; pl publish ASAP
    float pacc[4];
    #pragma unroll
    for (int rr = 0; rr < 4; rr++){
      float4 du = duR[rr];
      float4 tE = tER[rr];
      float4 up = upR[rr];
      float4 lo = loR[rr];
      float h_i = hni[rr], t_i = teni[rr];
      float4 nd, nt;
      float acc;
      { float o_ = h_i*tj.x - t_i*hj.x;
        float tn = fmaf(s_b, o_ - tE.x, tE.x);
        float dn = fmaf(tau, fmaf(m_b, tn, -du.x), du.x);
        dn = fminf(dn, up.x); dn = fmaxf(dn, lo.x);
        nt.x = tn; nd.x = dn; acc = dn*hj.x; }
      { float o_ = h_i*tj.y - t_i*hj.y;
        float tn = fmaf(s_b, o_ - tE.y, tE.y);
        float dn = fmaf(tau, fmaf(m_b, tn, -du.y), du.y);
        dn = fminf(dn, up.y); dn = fmaxf(dn, lo.y);
        nt.y = tn; nd.y = dn; acc = fmaf(dn, hj.y, acc); }
      { float o_ = h_i*tj.z - t_i*hj.z;
        float tn = fmaf(s_b, o_ - tE.z, tE.z);
        float dn = fmaf(tau, fmaf(m_b, tn, -du.z), du.z);
        dn = fminf(dn, up.z); dn = fmaxf(dn, lo.z);
        nt.z = tn; nd.z = dn; acc = fmaf(dn, hj.z, acc); }
      { float o_ = h_i*tj.w - t_i*hj.w;
        float tn = fmaf(s_b, o_ - tE.w, tE.w);
        float dn = fmaf(tau, fmaf(m_b, tn, -du.w), du.w);
        dn = fminf(dn, up.w); dn = fmaxf(dn, lo.w);
        nt.w = tn; nd.w = dn; acc = fmaf(dn, hj.w, acc); }
      duR[rr] = nd;
      tER[rr] = nt;
      pacc[rr] = acc;
    }
    pacc[0] = wred(pacc[0]); pacc[1] = wred(pacc[1]);
    pacc[2] = wred(pacc[2]); pacc[3] = wred(pacc[3]);
    if (t < T_-1 && lane==63){
      u64* pd = g_plp + pn*(B_*H_) + b*H_ + c*16 + wv;
      pstore(pd + 0,  t+1, sp_a*pacc[0]);
      pstore(pd + 4,  t+1, sp_a*pacc[1]);
      pstore(pd + 8,  t+1, sp_a*pacc[2]);
      pstore(pd + 12, t+1, sp_a*pacc[3]);
    }

    // ---- Wh(t+1): AFTER pl publish (wh path had ~700cy slack; rebalance)
    if (t < T_-1 && tid < 192){
      const int w  = tid >> 6;
      const int l4 = lane & 3;
      const float4* wb  = ((const float4*)wrow_s) + w*1024;
      float ax=0.f, ay=0.f, az=0.f, aw=0.f;
      #pragma unroll
      for (int u = 0; u < 16; u++){
        float4 w4 = wb[u*64 + lane];
        float4 hv = hn4[u*4 + l4];
        ax = fmaf(w4.x,hv.x,ax); ay = fmaf(w4.y,hv.y,ay);
        az = fmaf(w4.z,hv.z,az); aw = fmaf(w4.w,hv.w,aw);
      }
      float acc = (ax+ay)+(az+aw);
      acc = red4(acc);
      if (l4==3) pstore(&g_whp[pn*(B_*H3_) + b*H3_ + c*48 + w*16 + (lane>>2)],
                        t+1, acc + bh2h_reg);
    }

    // ---- outputs: AFTER publishes (off the inter-block serial path)
    if (tid < 16) out[OFF_OUTS + ((size_t)(t*B_+b))*H_ + c*16 + tid] = hn_s[c*16 + tid];
    if (tid < 2)  out[OFF_MODS + ((size_t)(t*B_+b))*R_ + c*2 + tid]  = mod_s[c*2 + tid];
    if (t == T_-1){
      #pragma unroll
      for (int rr = 0; rr < 4; rr++){
        int i = c*16 + rr*4 + wv;
        size_t rowo = ((size_t)(b*H_ + i))*H_;
        ((float4*)(out + OFF_DU + rowo))[lane] = duR[rr];
        ((float4*)(out + OFF_TT + rowo))[lane] = tER[rr];
      }
      if (c == 0){
        out[OFF_V  + b*H_ + tid] = v_r;
        out[OFF_H  + b*H_ + tid] = h_r;
        out[OFF_TE + b*H_ + tid] = te_r;
      }
    }
    // no end-of-step barrier: next iteration's poll enforces all ordering
  }

  // ---- self-reset of group counters for the next launch.
  __syncthreads();
  if (threadIdx.x == 0){
    int d = __hip_atomic_fetch_add(dctr, 1, __ATOMIC_RELAXED, __HIP_MEMORY_SCOPE_AGENT);
    if (d == 15){
      __hip_atomic_store(ctr,  0, __ATOMIC_RELAXED, __HIP_MEMORY_SCOPE_AGENT);
      __hip_atomic_store(dctr, 0, __ATOMIC_RELAXED, __HIP_MEMORY_SCOPE_AGENT);
    }
  }
}

extern "C" void kernel_launch(void* const* d_in, const int* in_sizes, int n_in,
                              void* d_out, int out_size, void* d_ws, size_t ws_size,
                              hipStream_t stream)
{
  const float* x      = (const float*)d_in[0];
  const float* h0     = (const float*)d_in[1];
  const float* v0     = (const float*)d_in[2];
  const float* dU0    = (const float*)d_in[3];
  const float* te0    = (const float*)d_in[4];
  const float* tE0    = (const float*)d_in[5];
  const float* Wx2h   = (const float*)d_in[6];
  const float* bx2h   = (const float*)d_in[7];
  const float* Wh2h   = (const float*)d_in[8];
  const float* bh2h   = (const float*)d_in[9];
  const float* lnxg   = (const float*)d_in[10];
  const float* lnxb   = (const float*)d_in[11];
  const float* lnhg   = (const float*)d_in[12];
  const float* lnhb   = (const float*)d_in[13];
  const float* Wh2mod = (const float*)d_in[14];
  const float* bh2mod = (const float*)d_in[15];
  const float* Wmod2h = (const float*)d_in[16];
  const float* bmod2h = (const float*)d_in[17];
  const float* alpha  = (const float*)d_in[18];
  const float* tauU   = (const float*)d_in[19];
  float* out = (float*)d_out;

  sgru_kernel<<<dim3(256), dim3(256), 0, stream>>>(
      x, h0, v0, dU0, te0, tE0, Wx2h, bx2h, Wh2h, bh2h,
      lnxg, lnxb, lnhg, lnhb, Wh2mod, bh2mod, Wmod2h, bmod2h,
      alpha, tauU, out);
}